// Round 1
// baseline (3026.542 us; speedup 1.0000x reference)
//
#include <hip/hip_runtime.h>

constexpr int N_NODES = 50000;
constexpr int N_EDGES = 1600000;
// DIM_H = 128, N_HEADS = 8, OUT_DIM = 16

// ---------------------------------------------------------------------------
// Stage W (128x128, k-major) into LDS as W^T with XOR-swizzled 16B chunks:
// element W[k][d] lives at WT[d*128 + ((k>>2)^(d&31))*4 + (k&3)].
// Read of (d, kc) -> W[4kc..4kc+3][d] is a 16B-aligned float4; across a wave
// (d = lane / lane+64) the swizzle permutes chunks so all 32 banks are hit
// evenly (8 words/bank for 64 lanes = LDS minimum). No padding -> 64 KB.
// ---------------------------------------------------------------------------
__device__ __forceinline__ void stage_W_swizzled(const float* __restrict__ W,
                                                 float* WT, int tid) {
    const float4* W4 = (const float4*)W;
#pragma unroll
    for (int i = 0; i < 16; ++i) {
        int f = tid + 256 * i;      // float4 index 0..4095
        int k = f >> 5;             // row of W (k index)
        int d0 = (f & 31) << 2;     // col of W (d index)
        float4 w = W4[f];
        int kc = k >> 2, kr = k & 3;
        float vals[4] = {w.x, w.y, w.z, w.w};
#pragma unroll
        for (int j = 0; j < 4; ++j) {
            int d = d0 + j;
            WT[d * 128 + ((kc ^ (d & 31)) << 2) + kr] = vals[j];
        }
    }
}

__device__ __forceinline__ float4 read_WT(const float* WT, int d, int kc) {
    return *(const float4*)&WT[d * 128 + ((kc ^ (d & 31)) << 2)];
}

// ---------------------------------------------------------------------------
// Node projection: OUT[M x 128] = A[M x 128] @ W[128 x 128], fp32.
// Block = 256 thr (4 waves), 32 rows/block, wave owns 8 rows,
// lane owns output dims (lane, lane+64). LDS = 64KB WT + 16KB A = 80KB
// -> 2 blocks/CU.
// ---------------------------------------------------------------------------
__global__ __launch_bounds__(256) void proj_kernel(const float* __restrict__ A,
                                                   const float* __restrict__ W,
                                                   float* __restrict__ OUT, int M) {
    __shared__ float WT[128 * 128];
    __shared__ float As[32 * 128];
    int tid = threadIdx.x;
    stage_W_swizzled(W, WT, tid);
    int base = blockIdx.x * 32;
    const float4 zero4 = {0.f, 0.f, 0.f, 0.f};
#pragma unroll
    for (int i = 0; i < 4; ++i) {
        int f = tid + 256 * i;      // float4 index 0..1023
        int row = f >> 5, c4 = f & 31;
        float4 v = (base + row < M) ? ((const float4*)A)[(size_t)(base + row) * 32 + c4]
                                    : zero4;
        *(float4*)&As[row * 128 + (c4 << 2)] = v;
    }
    __syncthreads();
    int wave = tid >> 6, lane = tid & 63;
    float acc0[8] = {}, acc1[8] = {};
    for (int kc = 0; kc < 32; ++kc) {
        float4 w0 = read_WT(WT, lane, kc);
        float4 w1 = read_WT(WT, lane + 64, kc);
#pragma unroll
        for (int r = 0; r < 8; ++r) {
            float4 a = *(float4*)&As[(wave * 8 + r) * 128 + (kc << 2)];
            acc0[r] += a.x * w0.x + a.y * w0.y + a.z * w0.z + a.w * w0.w;
            acc1[r] += a.x * w1.x + a.y * w1.y + a.z * w1.z + a.w * w1.w;
        }
    }
#pragma unroll
    for (int r = 0; r < 8; ++r) {
        int row = base + wave * 8 + r;
        if (row < M) {
            OUT[(size_t)row * 128 + lane] = acc0[r];
            OUT[(size_t)row * 128 + lane + 64] = acc1[r];
        }
    }
}

// ---------------------------------------------------------------------------
// Fused edge kernel: Eh = edge_attr @ WE computed in registers (never stored),
// then score = exp(clip(sum_d K[src]*Q[dst]*Eh * 0.25, -5, 5)) per head,
// atomic scatter of V[src]*score onto wV[dst] and score onto Z[dst].
// Lane ℓ owns dims (ℓ, ℓ+64) -> heads (ℓ>>4, (ℓ>>4)+4); per-head reduction is
// shfl_xor over the 16-lane group.
// ---------------------------------------------------------------------------
__global__ __launch_bounds__(256) void edge_kernel(const float* __restrict__ EA,
                                                   const float* __restrict__ WE,
                                                   const int* __restrict__ eidx,
                                                   const float* __restrict__ Qh,
                                                   const float* __restrict__ Kh,
                                                   const float* __restrict__ Vh,
                                                   float* __restrict__ wV,
                                                   float* __restrict__ Z) {
    __shared__ float WT[128 * 128];
    __shared__ float As[32 * 128];
    int tid = threadIdx.x;
    stage_W_swizzled(WE, WT, tid);
    int base = blockIdx.x * 32;                 // 1.6M % 32 == 0, no guards
#pragma unroll
    for (int i = 0; i < 4; ++i) {
        int f = tid + 256 * i;
        int row = f >> 5, c4 = f & 31;
        *(float4*)&As[row * 128 + (c4 << 2)] =
            ((const float4*)EA)[(size_t)(base + row) * 32 + c4];
    }
    __syncthreads();
    int wave = tid >> 6, lane = tid & 63;
    float e0[8] = {}, e1[8] = {};
    for (int kc = 0; kc < 32; ++kc) {
        float4 w0 = read_WT(WT, lane, kc);
        float4 w1 = read_WT(WT, lane + 64, kc);
#pragma unroll
        for (int r = 0; r < 8; ++r) {
            float4 a = *(float4*)&As[(wave * 8 + r) * 128 + (kc << 2)];
            e0[r] += a.x * w0.x + a.y * w0.y + a.z * w0.z + a.w * w0.w;
            e1[r] += a.x * w1.x + a.y * w1.y + a.z * w1.z + a.w * w1.w;
        }
    }
    const float inv_sqrt_d = 0.25f;             // 1/sqrt(16)
    int head0 = lane >> 4;
#pragma unroll
    for (int r = 0; r < 8; ++r) {
        int e = base + wave * 8 + r;
        int src = eidx[e];
        int dst = eidx[N_EDGES + e];
        size_t so = (size_t)src * 128, dofs = (size_t)dst * 128;
        float k0 = Kh[so + lane], k1 = Kh[so + lane + 64];
        float q0 = Qh[dofs + lane], q1 = Qh[dofs + lane + 64];
        float v0 = Vh[so + lane], v1 = Vh[so + lane + 64];
        float p0 = k0 * q0 * e0[r];
        float p1 = k1 * q1 * e1[r];
#pragma unroll
        for (int off = 1; off < 16; off <<= 1) {
            p0 += __shfl_xor(p0, off);
            p1 += __shfl_xor(p1, off);
        }
        float s0 = expf(fminf(fmaxf(p0 * inv_sqrt_d, -5.f), 5.f));
        float s1 = expf(fminf(fmaxf(p1 * inv_sqrt_d, -5.f), 5.f));
        atomicAdd(&wV[dofs + lane], v0 * s0);
        atomicAdd(&wV[dofs + lane + 64], v1 * s1);
        if ((lane & 15) == 0) {
            atomicAdd(&Z[dst * 8 + head0], s0);
            atomicAdd(&Z[dst * 8 + head0 + 4], s1);
        }
    }
}

// ---------------------------------------------------------------------------
// h_out = wV / (Z + 1e-6)
// ---------------------------------------------------------------------------
__global__ __launch_bounds__(256) void norm_kernel(const float* __restrict__ wV,
                                                   const float* __restrict__ Z,
                                                   float* __restrict__ out) {
    int i = blockIdx.x * 256 + threadIdx.x;     // out_size = 6.4M, exact grid
    int n = i >> 7;
    int head = (i & 127) >> 4;
    out[i] = wV[i] / (Z[n * 8 + head] + 1e-6f);
}

extern "C" void kernel_launch(void* const* d_in, const int* in_sizes, int n_in,
                              void* d_out, int out_size, void* d_ws, size_t ws_size,
                              hipStream_t stream) {
    const float* h  = (const float*)d_in[0];
    const float* ea = (const float*)d_in[1];
    const float* WQ = (const float*)d_in[2];
    const float* WK = (const float*)d_in[3];
    const float* WV = (const float*)d_in[4];
    const float* WE = (const float*)d_in[5];
    const int*  eix = (const int*)d_in[6];

    float* ws = (float*)d_ws;
    float* Qh = ws;                  // 6.4M floats
    float* Kh = ws + 6400000;        // 6.4M
    float* Vh = ws + 12800000;       // 6.4M
    float* wV = ws + 19200000;       // 6.4M
    float* Z  = ws + 25600000;       // 400K
    // total 26.0M floats = 104 MB of ws

    // zero the accumulators (ws is poisoned 0xAA before every timed call)
    hipMemsetAsync(wV, 0, (size_t)(6400000 + 400000) * sizeof(float), stream);

    int nb = (N_NODES + 31) / 32;    // 1563
    proj_kernel<<<nb, 256, 0, stream>>>(h, WQ, Qh, N_NODES);
    proj_kernel<<<nb, 256, 0, stream>>>(h, WK, Kh, N_NODES);
    proj_kernel<<<nb, 256, 0, stream>>>(h, WV, Vh, N_NODES);

    edge_kernel<<<N_EDGES / 32, 256, 0, stream>>>(ea, WE, eix, Qh, Kh, Vh, wV, Z);

    norm_kernel<<<out_size / 256, 256, 0, stream>>>(wV, Z, (float*)d_out);
}